// Round 1
// 458.591 us; speedup vs baseline: 1.0842x; 1.0842x over previous
//
#include <hip/hip_runtime.h>
#include <math.h>

typedef __attribute__((ext_vector_type(8))) short short8;
typedef __attribute__((ext_vector_type(4))) float floatx4;

__device__ inline unsigned f2bf1(float f) {
    union { float f; unsigned u; } v; v.f = f;
    return (v.u + 0x8000u) >> 16;   // round-half-up to bf16
}

__device__ inline short8 pack8(float4 a, float4 b) {
    short8 r;
    r[0] = (short)f2bf1(a.x); r[1] = (short)f2bf1(a.y);
    r[2] = (short)f2bf1(a.z); r[3] = (short)f2bf1(a.w);
    r[4] = (short)f2bf1(b.x); r[5] = (short)f2bf1(b.y);
    r[6] = (short)f2bf1(b.z); r[7] = (short)f2bf1(b.w);
    return r;
}

__device__ inline float gelu1(float x) {
    return 0.5f * x * (1.0f + erff(x * 0.70710678118654752f));
}

// -------- segment-average: x (16,128,512) -> xcf (32, 2048), m = b*16 + a ----
__global__ __launch_bounds__(128) void avg_k(const float* __restrict__ x,
                                             float* __restrict__ xcf) {
    int blk = blockIdx.x;            // a*128 + b
    int a = blk >> 7, b = blk & 127;
    int t = threadIdx.x;
    const float4 v = *(const float4*)(x + ((size_t)a * 128 + b) * 512 + t * 4);
    float s = v.x + v.y + v.z + v.w;
    s += __shfl_xor(s, 1);
    s += __shfl_xor(s, 2);
    if ((t & 3) == 0) {
        int seg = t >> 2;            // 0..31
        xcf[seg * 2048 + b * 16 + a] = s * (1.0f / 16.0f);
    }
}

// -------- LN stats only: per row of 2048, write {mean, rstd} (two-pass) ------
__global__ __launch_bounds__(256) void stats_k(const float* __restrict__ Sin,
                                               float* __restrict__ st) {
    __shared__ float red[8];
    const int row = blockIdx.x, t = threadIdx.x;
    const float* xr = Sin + (size_t)row * 2048;
    float4 v0 = *(const float4*)(xr + t * 4);
    float4 v1 = *(const float4*)(xr + 1024 + t * 4);
    float s = v0.x + v0.y + v0.z + v0.w + v1.x + v1.y + v1.z + v1.w;
    for (int o = 32; o; o >>= 1) s += __shfl_down(s, o);
    if ((t & 63) == 0) red[t >> 6] = s;
    __syncthreads();
    float mean = (red[0] + red[1] + red[2] + red[3]) * (1.0f / 2048.0f);
    float d0 = v0.x - mean, d1 = v0.y - mean, d2 = v0.z - mean, d3 = v0.w - mean;
    float e0 = v1.x - mean, e1 = v1.y - mean, e2 = v1.z - mean, e3 = v1.w - mean;
    float s2 = d0*d0 + d1*d1 + d2*d2 + d3*d3 + e0*e0 + e1*e1 + e2*e2 + e3*e3;
    for (int o = 32; o; o >>= 1) s2 += __shfl_down(s2, o);
    if ((t & 63) == 0) red[4 + (t >> 6)] = s2;
    __syncthreads();
    if (t == 0) {
        float var = (red[4] + red[5] + red[6] + red[7]) * (1.0f / 2048.0f);
        st[row * 2]     = mean;
        st[row * 2 + 1] = 1.0f / sqrtf(var + 1e-5f);
    }
}

// -------- thin GEMM: C[32,N] += f(X)[32,K] @ W[N,K]^T, split-K via atomics ---
// STAGE: 0 plain; 1 LN via stats/sg/sb; 11 LN + residual; 2 cumsum over rows;
//        3 gelu(X + sg[k])
// EPI:   0 plain; 1 +ebias[n] (by==0); 2 +sinusoidal posbias (by==0)
// NT: wave n-tiles of 16 (block covers NT*64 output cols, 4 waves)
template<int KCHUNK, int NT, int STAGE, int EPI>
__global__ __launch_bounds__(256) void gemm_k(const float* __restrict__ X,
                                              const float* __restrict__ W,
                                              float* __restrict__ C,
                                              const float* __restrict__ ebias,
                                              const float* __restrict__ stats,
                                              const float* __restrict__ sg,
                                              const float* __restrict__ sb,
                                              int N, int K) {
    constexpr int PITCH = KCHUNK + 8;        // +8 bf16 = 16B pad, kills bank conflicts
    __shared__ unsigned short Xs[32 * PITCH];
    const int tid = threadIdx.x;
    const int bx = blockIdx.x, by = blockIdx.y;
    const int kb0 = by * KCHUNK;

    if constexpr (STAGE == 2) {
        // fused inclusive prefix-sum over the 32 rows, one column per thread
        for (int c = tid; c < KCHUNK; c += 256) {
            const float* vp = X + kb0 + c;
            float run = 0.f;
#pragma unroll
            for (int r = 0; r < 32; r++) {
                run += vp[(size_t)r * K];
                Xs[r * PITCH + c] = (unsigned short)f2bf1(run);
            }
        }
    } else {
        constexpr int NF4 = 32 * (KCHUNK / 4);
        for (int f = tid; f < NF4; f += 256) {
            const int row = f / (KCHUNK / 4), c4 = f % (KCHUNK / 4);
            const int k0 = kb0 + c4 * 4;
            float4 v = *(const float4*)(X + (size_t)row * K + k0);
            if constexpr (STAGE == 1 || STAGE == 11) {
                const float m = stats[row * 2], rs = stats[row * 2 + 1];
                const float4 gg = *(const float4*)(sg + k0);
                const float4 bb = *(const float4*)(sb + k0);
                float4 o;
                o.x = (v.x - m) * rs * gg.x + bb.x;
                o.y = (v.y - m) * rs * gg.y + bb.y;
                o.z = (v.z - m) * rs * gg.z + bb.z;
                o.w = (v.w - m) * rs * gg.w + bb.w;
                if constexpr (STAGE == 11) {
                    o.x += v.x; o.y += v.y; o.z += v.z; o.w += v.w;
                }
                v = o;
            }
            if constexpr (STAGE == 3) {
                const float4 bb = *(const float4*)(sg + k0);
                v.x = gelu1(v.x + bb.x);
                v.y = gelu1(v.y + bb.y);
                v.z = gelu1(v.z + bb.z);
                v.w = gelu1(v.w + bb.w);
            }
            ushort4 p;
            p.x = (unsigned short)f2bf1(v.x);
            p.y = (unsigned short)f2bf1(v.y);
            p.z = (unsigned short)f2bf1(v.z);
            p.w = (unsigned short)f2bf1(v.w);
            *(ushort4*)&Xs[row * PITCH + c4 * 4] = p;
        }
    }
    __syncthreads();

    const int w = tid >> 6, lane = tid & 63;
    const int q = lane >> 4, r16 = lane & 15;
    const int nb = bx * (NT * 64) + w * (NT * 16);
    floatx4 acc[2][NT] = {};
    const float* wp0 = W + (size_t)(nb + r16) * K + kb0 + q * 8;
    const float* wp1 = W + (size_t)(nb + 16 + r16) * K + kb0 + q * 8;

#pragma unroll
    for (int kk = 0; kk < KCHUNK; kk += 32) {
        short8 a0 = *(const short8*)&Xs[r16 * PITCH + kk + q * 8];
        short8 a1 = *(const short8*)&Xs[(16 + r16) * PITCH + kk + q * 8];
        {
            float4 u0 = *(const float4*)(wp0 + kk);
            float4 u1 = *(const float4*)(wp0 + kk + 4);
            short8 bf = pack8(u0, u1);
            acc[0][0] = __builtin_amdgcn_mfma_f32_16x16x32_bf16(a0, bf, acc[0][0], 0, 0, 0);
            acc[1][0] = __builtin_amdgcn_mfma_f32_16x16x32_bf16(a1, bf, acc[1][0], 0, 0, 0);
        }
        if constexpr (NT == 2) {
            float4 u0 = *(const float4*)(wp1 + kk);
            float4 u1 = *(const float4*)(wp1 + kk + 4);
            short8 bf = pack8(u0, u1);
            acc[0][1] = __builtin_amdgcn_mfma_f32_16x16x32_bf16(a0, bf, acc[0][1], 0, 0, 0);
            acc[1][1] = __builtin_amdgcn_mfma_f32_16x16x32_bf16(a1, bf, acc[1][1], 0, 0, 0);
        }
    }

#pragma unroll
    for (int mt = 0; mt < 2; mt++)
#pragma unroll
        for (int nt = 0; nt < NT; nt++)
#pragma unroll
            for (int e = 0; e < 4; e++) {
                int i = mt * 16 + q * 4 + e;          // C/D: row = quad*4 + reg
                int n = nb + nt * 16 + r16;           //      col = lane&15
                float v = acc[mt][nt][e];
                if (EPI == 1 && by == 0) v += ebias[n];
                if (EPI == 2 && by == 0) {
                    int ne = n & ~1;
                    float ang = (float)i * __expf(-(float)ne * (9.210340371976184f / 1024.0f));
                    v += (n & 1) ? cosf(ang) : sinf(ang);
                }
                atomicAdd(C + (size_t)i * N + n, v);
            }
}

extern "C" void kernel_launch(void* const* d_in, const int* in_sizes, int n_in,
                              void* d_out, int out_size, void* d_ws, size_t ws_size,
                              hipStream_t stream) {
    const float* x      = (const float*)d_in[0];
    const float* weight = (const float*)d_in[1];
    // d_in[2] = Wq, d_in[3] = Wk: dead (softmax over a scalar == 1)
    const float* Wv     = (const float*)d_in[4];
    const float* Wo     = (const float*)d_in[5];
    const float* ln1g   = (const float*)d_in[6];
    const float* ln1b   = (const float*)d_in[7];
    const float* ln2g   = (const float*)d_in[8];
    const float* ln2b   = (const float*)d_in[9];
    const float* fc1w   = (const float*)d_in[10];
    const float* fc1b   = (const float*)d_in[11];
    const float* fc2w   = (const float*)d_in[12];
    const float* fc2b   = (const float*)d_in[13];
    float* ws  = (float*)d_ws;
    float* xcf = ws;                 // 32*2048
    float* S   = ws + 65536;         // 32*2048
    float* V   = ws + 131072;        // 32*2048
    float* H   = ws + 196608;        // 32*8192
    float* st1 = ws + 458752;        // 32*2  {mean, rstd}
    float* st2 = ws + 458816;        // 32*2
    float* out = (float*)d_out;

    avg_k<<<2048, 128, 0, stream>>>(x, xcf);

    hipMemsetAsync(S, 0, 65536 * 4, stream);
    gemm_k<128, 1, 0, 2><<<dim3(32, 16), 256, 0, stream>>>(
        xcf, weight, S, nullptr, nullptr, nullptr, nullptr, 2048, 2048);

    for (int a = 0; a < 3; a++) {
        // xn = LN1(S); V = xn @ Wv[a]^T  (LN fused into staging)
        stats_k<<<32, 256, 0, stream>>>(S, st1);
        hipMemsetAsync(V, 0, 65536 * 4, stream);
        gemm_k<128, 1, 1, 0><<<dim3(32, 16), 256, 0, stream>>>(
            S, Wv + (size_t)a * 4194304, V, nullptr, st1, ln1g, ln1b, 2048, 2048);
        // S += cumsum_rows(V) @ Wo[a]^T  (prefix-sum fused into staging)
        gemm_k<128, 1, 2, 0><<<dim3(32, 16), 256, 0, stream>>>(
            V, Wo + (size_t)a * 4194304, S, nullptr, nullptr, nullptr, nullptr, 2048, 2048);
        // H = fc1_w @ (LN2(S)+S)  (LN+residual fused into staging)
        stats_k<<<32, 256, 0, stream>>>(S, st2);
        hipMemsetAsync(H, 0, 262144 * 4, stream);
        gemm_k<256, 1, 11, 0><<<dim3(128, 8), 256, 0, stream>>>(
            S, fc1w, H, nullptr, st2, ln2g, ln2b, 8192, 2048);
        // S/out = fc2_w @ gelu(H + fc1_b) + fc2_b  (bias+gelu fused into staging)
        float* Co = (a == 2) ? out : S;
        hipMemsetAsync(Co, 0, 65536 * 4, stream);
        gemm_k<256, 1, 3, 1><<<dim3(32, 32), 256, 0, stream>>>(
            H, fc2w, Co, fc2b, nullptr, fc1b, nullptr, 2048, 8192);
    }
}